// Round 5
// baseline (991.745 us; speedup 1.0000x reference)
//
#include <hip/hip_runtime.h>

// Problem constants (reference.py)
#define N_ENV 100000
#define DIM   400
#define MPTS  2000
#define NSTR  2000
#define NTRN  100

// GEMM tiling
#define BM 128
#define BN 128
#define NPAD 100096              // 782 * 128
#define KPAD 416                 // 13 * 32
#define MPAD 2048                // 16 * 128
#define KTILES 13
#define MTILES 16
#define NSTAGE (MTILES * KTILES) // 208 pipeline stages
#define LDST 424                 // LDS row stride in shorts (848 B -> 2-way bank alias, free)

typedef __attribute__((ext_vector_type(8))) short short8;
typedef __attribute__((ext_vector_type(4))) float float4v;

__device__ __forceinline__ unsigned short f2bf(float f) {
  union { float f; unsigned int u; } v; v.f = f;
  unsigned int u = v.u;
  u += 0x7fffu + ((u >> 16) & 1u);   // round-to-nearest-even
  return (unsigned short)(u >> 16);
}
__device__ __forceinline__ float bf2f(unsigned short s) {
  union { unsigned int u; float f; } v; v.u = ((unsigned int)s) << 16;
  return v.f;
}

// ---------------------------------------------------------------------------
// prep: wm[m] = weights[col_seg[m]] (0 in pad region), zero d_out
// ---------------------------------------------------------------------------
__global__ __launch_bounds__(256) void prep_kernel(
    const float* __restrict__ w, const int* __restrict__ col_seg,
    float* __restrict__ wm, float* __restrict__ out) {
  int t = blockIdx.x * 256 + threadIdx.x;
  if (t < MPAD) wm[t] = (t < MPTS) ? w[col_seg[t]] : 0.f;
  if (t < NSTR) out[t] = 0.f;
}

// ---------------------------------------------------------------------------
// B swizzle: fp32 support_points [MPTS,DIM] -> bf16 fragments in exact
// per-lane load order: Bsw[((mt*13+kt)*8+cf)*64+lane][e] =
//   B[mt*128+cf*16+(lane&15)][kt*32+(lane>>4)*8+e]  (0 outside MPTS/DIM)
// ---------------------------------------------------------------------------
__global__ __launch_bounds__(256) void bswz_kernel(
    const float* __restrict__ sp, short8* __restrict__ Bsw) {
  int u = blockIdx.x * 256 + threadIdx.x;     // < 208*8*64 = 106496
  int lane = u & 63;
  int v = u >> 6;          // ((mt*13+kt)*8+cf)
  int cf = v & 7;
  int w = v >> 3;          // mt*13+kt
  int kt = w % 13;
  int mt = w / 13;
  int col = mt * 128 + cf * 16 + (lane & 15);
  int kb  = kt * 32 + ((lane >> 4) << 3);
  short8 o = (short8){0, 0, 0, 0, 0, 0, 0, 0};
  if (col < MPTS && kb < DIM) {   // DIM divisible by 8: chunks never straddle
    const float* p = sp + (size_t)col * DIM + kb;
    float4 a = *(const float4*)p;
    float4 b = *(const float4*)(p + 4);
    o[0] = (short)f2bf(a.x); o[1] = (short)f2bf(a.y);
    o[2] = (short)f2bf(a.z); o[3] = (short)f2bf(a.w);
    o[4] = (short)f2bf(b.x); o[5] = (short)f2bf(b.y);
    o[6] = (short)f2bf(b.z); o[7] = (short)f2bf(b.w);
  }
  Bsw[u] = o;
}

// ---------------------------------------------------------------------------
// Fused kernel:
//  - Pass 1: coalesced fp32 A-band -> bf16 -> LDS (one sync).
//  - A fragments ds_read ONCE into regs (af[13][4]); row norm in-register
//    via shfl_xor(16,32); LDS dead afterwards, no more barriers.
//  - Main loop over 208 stages s = mt*13+kt: 4-deep rotating B prefetch
//    with slot = s&3 (write-after-consume invariant -> no collisions;
//    the round-4 slot=kt&3 scheme clobbered stage 12 at mt boundaries).
//    mt unrolled x4 so (mtu+kt)&3 is compile-time. Prefetch unconditional;
//    tail reads 4 dummy stages (padded in ws, never consumed).
//  - Epilogue per mt: vacc[row] += wm[col]*C^2; final shfl reduce + atomics.
// ---------------------------------------------------------------------------
__global__ __launch_bounds__(256, 1) void gemm_fused_kernel(
    const float* __restrict__ A,        // raw power_spectrum fp32 [N_ENV][DIM]
    const short8* __restrict__ Bsw,     // swizzled B fragments (+4 pad stages)
    const float* __restrict__ wm,       // [MPAD]
    const int* __restrict__ row_seg,    // [N_ENV]
    float* __restrict__ out) {          // [NSTR]
  extern __shared__ unsigned short As[];   // [128][LDST] = 108544 B

  const int tid  = threadIdx.x;
  const int lane = tid & 63;
  const int wid  = tid >> 6;
  const int wrow = wid >> 1;            // 0..1
  const int wcol = wid & 1;             // 0..1
  const long row_base = (long)blockIdx.x * BM;

  // ---- Pass 1: coalesced fp32 -> bf16 -> LDS (unnormalized) --------------
  {
    const float4* Ag = (const float4*)(A + row_base * DIM);
    int rows_valid = (int)(N_ENV - row_base);
    if (rows_valid > BM) rows_valid = BM;
#pragma unroll 5
    for (int c = tid; c < BM * (DIM / 4); c += 256) {  // 12800 float4 chunks
      int row = c / 100;                               // 100 float4 per row
      int kc  = c - row * 100;
      uint2 packed = (uint2){0u, 0u};
      if (row < rows_valid) {
        float4 v = Ag[c];
        packed.x = (unsigned int)f2bf(v.x) | ((unsigned int)f2bf(v.y) << 16);
        packed.y = (unsigned int)f2bf(v.z) | ((unsigned int)f2bf(v.w) << 16);
      }
      *(uint2*)&As[row * LDST + kc * 4] = packed;
    }
    // Zero K-pad tail [400,424): frags at kt=12, koff 16/24 read up to 416.
    if (tid < BM) {
      uint4 z = (uint4){0u, 0u, 0u, 0u};
      uint4* zp = (uint4*)&As[tid * LDST + 400];
      zp[0] = z; zp[1] = z; zp[2] = z;
    }
  }
  __syncthreads();

  // ---- A fragments -> registers, normalize in-register -------------------
  const int frow = lane & 15;
  const int koff = (lane >> 4) * 8;
  short8 af[KTILES][4];
#pragma unroll
  for (int i = 0; i < 4; ++i) {
    const unsigned short* rp = &As[(wrow * 64 + i * 16 + frow) * LDST + koff];
    float ss = 0.f;
#pragma unroll
    for (int kt = 0; kt < KTILES; ++kt) {
      short8 v = *(const short8*)(rp + kt * 32);
      af[kt][i] = v;
#pragma unroll
      for (int e = 0; e < 8; ++e) {
        float f = bf2f((unsigned short)v[e]);
        ss += f * f;
      }
    }
    // lanes {frow, frow+16, frow+32, frow+48} together hold the full row
    ss += __shfl_xor(ss, 16);
    ss += __shfl_xor(ss, 32);
    float rn = (ss > 0.f) ? rsqrtf(ss) : 0.f;
#pragma unroll
    for (int kt = 0; kt < KTILES; ++kt) {
      short8 v = af[kt][i], o;
#pragma unroll
      for (int e = 0; e < 8; ++e)
        o[e] = (short)f2bf(bf2f((unsigned short)v[e]) * rn);
      af[kt][i] = o;
    }
  }
  // LDS dead from here; no more barriers.

  float vacc[4][4];
#pragma unroll
  for (int i = 0; i < 4; ++i)
#pragma unroll
    for (int r = 0; r < 4; ++r) vacc[i][r] = 0.f;

  // ---- B stream: 4-deep rotating register prefetch, slot = stage&3 -------
  const short8* Bb = Bsw + (size_t)(wcol * 4) * 64 + lane;  // + j*64 + s*512
  short8 bf[4][4];
#pragma unroll
  for (int p = 0; p < 4; ++p)                 // stages 0..3 -> slots 0..3
#pragma unroll
    for (int j = 0; j < 4; ++j)
      bf[p][j] = Bb[(size_t)p * 512 + j * 64];

#pragma unroll 1
  for (int mt4 = 0; mt4 < 4; ++mt4) {
    const short8* Bblk = Bb + (size_t)mt4 * (4 * KTILES * 512);
#pragma unroll
    for (int mtu = 0; mtu < 4; ++mtu) {
      float4v acc[4][4];
#pragma unroll
      for (int i = 0; i < 4; ++i)
#pragma unroll
        for (int j = 0; j < 4; ++j) acc[i][j] = (float4v){0.f, 0.f, 0.f, 0.f};

#pragma unroll
      for (int kt = 0; kt < KTILES; ++kt) {
        const int slot = (mtu + kt) & 3;      // == (global stage) & 3
        // consume stage (mt4*4+mtu, kt)
#pragma unroll
        for (int i = 0; i < 4; ++i)
#pragma unroll
          for (int j = 0; j < 4; ++j)
            acc[i][j] = __builtin_amdgcn_mfma_f32_16x16x32_bf16(
                af[kt][i], bf[slot][j], acc[i][j], 0, 0, 0);
        // prefetch stage s+4 into the slot just consumed ((s+4)&3 == s&3)
#pragma unroll
        for (int j = 0; j < 4; ++j)
          bf[slot][j] = Bblk[(size_t)(mtu * KTILES + kt + 4) * 512 + j * 64];
      }

      // epilogue: vacc[row] += wm[col] * C^2 over this wave's 4 col-frags
      const int mtb = (mt4 * 4 + mtu) * BN;
      float wmv[4];
#pragma unroll
      for (int j = 0; j < 4; ++j)
        wmv[j] = wm[mtb + wcol * 64 + j * 16 + frow];
#pragma unroll
      for (int i = 0; i < 4; ++i)
#pragma unroll
        for (int r = 0; r < 4; ++r) {
          float s = 0.f;
#pragma unroll
          for (int j = 0; j < 4; ++j) {
            float c = acc[i][j][r];
            s += wmv[j] * c * c;
          }
          vacc[i][r] += s;
        }
    }
  }

  // cross-lane reduce over 16-lane groups (same C/D rows), then atomics
#pragma unroll
  for (int i = 0; i < 4; ++i)
#pragma unroll
    for (int r = 0; r < 4; ++r) {
      float s = vacc[i][r];
      s += __shfl_xor(s, 1);
      s += __shfl_xor(s, 2);
      s += __shfl_xor(s, 4);
      s += __shfl_xor(s, 8);
      if ((lane & 15) == 0) {
        long n = row_base + wrow * 64 + i * 16 + (lane >> 4) * 4 + r;
        if (n < N_ENV) atomicAdd(&out[row_seg[n]], s);
      }
    }
}

// ---------------------------------------------------------------------------
extern "C" void kernel_launch(void* const* d_in, const int* in_sizes, int n_in,
                              void* d_out, int out_size, void* d_ws, size_t ws_size,
                              hipStream_t stream) {
  const float* ps      = (const float*)d_in[0];  // [N_ENV, DIM]
  const float* sp      = (const float*)d_in[1];  // [MPTS, DIM]
  const float* w       = (const float*)d_in[2];  // [1, NTRN]
  // d_in[3] = all_species: unused by the reference
  const int*   row_seg = (const int*)d_in[4];    // [N_ENV]
  const int*   col_seg = (const int*)d_in[5];    // [MPTS]
  float* out = (float*)d_out;                    // [NSTR]

  char* ws = (char*)d_ws;
  // 208 real stages + 4 pad stages (tail prefetch reads them, never consumed)
  const size_t B_BYTES = (size_t)(NSTAGE + 4) * 512 * 16;  // 1,736,704
  short8* Bsw = (short8*)ws;
  float*  wm  = (float*)(ws + B_BYTES);

  const int LDS_BYTES = BM * LDST * 2;   // 108544
  (void)hipFuncSetAttribute((const void*)gemm_fused_kernel,
                            hipFuncAttributeMaxDynamicSharedMemorySize,
                            LDS_BYTES);

  prep_kernel<<<MPAD / 256, 256, 0, stream>>>(w, col_seg, wm, out);
  bswz_kernel<<<(NSTAGE * 8 * 64) / 256, 256, 0, stream>>>(sp, Bsw);
  gemm_fused_kernel<<<NPAD / BM, 256, LDS_BYTES, stream>>>(ps, Bsw, wm, row_seg, out);
}

// Round 6
// 956.259 us; speedup vs baseline: 1.0371x; 1.0371x over previous
//
#include <hip/hip_runtime.h>

// Problem constants (reference.py)
#define N_ENV 100000
#define DIM   400
#define MPTS  2000
#define NSTR  2000
#define NTRN  100

// GEMM tiling
#define BM 128
#define BN 128
#define NPAD 100096              // 782 * 128
#define KPAD 416                 // 13 * 32
#define MPAD 2048                // 16 * 128
#define KTILES 13
#define MTILES 16
#define NSTAGE (MTILES * KTILES) // 208 pipeline stages
#define LDST 424                 // LDS row stride in shorts (848 B -> 2-way bank alias, free)

typedef __attribute__((ext_vector_type(8))) short short8;
typedef __attribute__((ext_vector_type(4))) float float4v;

__device__ __forceinline__ unsigned short f2bf(float f) {
  union { float f; unsigned int u; } v; v.f = f;
  unsigned int u = v.u;
  u += 0x7fffu + ((u >> 16) & 1u);   // round-to-nearest-even
  return (unsigned short)(u >> 16);
}
__device__ __forceinline__ float bf2f(unsigned short s) {
  union { unsigned int u; float f; } v; v.u = ((unsigned int)s) << 16;
  return v.f;
}

// ---------------------------------------------------------------------------
// prep: wm[m] = weights[col_seg[m]] (0 in pad region), zero d_out
// ---------------------------------------------------------------------------
__global__ __launch_bounds__(256) void prep_kernel(
    const float* __restrict__ w, const int* __restrict__ col_seg,
    float* __restrict__ wm, float* __restrict__ out) {
  int t = blockIdx.x * 256 + threadIdx.x;
  if (t < MPAD) wm[t] = (t < MPTS) ? w[col_seg[t]] : 0.f;
  if (t < NSTR) out[t] = 0.f;
}

// ---------------------------------------------------------------------------
// B swizzle: fp32 support_points [MPTS,DIM] -> bf16 fragments in exact
// per-lane load order: Bsw[((mt*13+kt)*8+cf)*64+lane][e] =
//   B[mt*128+cf*16+(lane&15)][kt*32+(lane>>4)*8+e]  (0 outside MPTS/DIM)
// ---------------------------------------------------------------------------
__global__ __launch_bounds__(256) void bswz_kernel(
    const float* __restrict__ sp, short8* __restrict__ Bsw) {
  int u = blockIdx.x * 256 + threadIdx.x;     // < 208*8*64 = 106496
  int lane = u & 63;
  int v = u >> 6;          // ((mt*13+kt)*8+cf)
  int cf = v & 7;
  int w = v >> 3;          // mt*13+kt
  int kt = w % 13;
  int mt = w / 13;
  int col = mt * 128 + cf * 16 + (lane & 15);
  int kb  = kt * 32 + ((lane >> 4) << 3);
  short8 o = (short8){0, 0, 0, 0, 0, 0, 0, 0};
  if (col < MPTS && kb < DIM) {   // DIM divisible by 8: chunks never straddle
    const float* p = sp + (size_t)col * DIM + kb;
    float4 a = *(const float4*)p;
    float4 b = *(const float4*)(p + 4);
    o[0] = (short)f2bf(a.x); o[1] = (short)f2bf(a.y);
    o[2] = (short)f2bf(a.z); o[3] = (short)f2bf(a.w);
    o[4] = (short)f2bf(b.x); o[5] = (short)f2bf(b.y);
    o[6] = (short)f2bf(b.z); o[7] = (short)f2bf(b.w);
  }
  Bsw[u] = o;
}

// ---------------------------------------------------------------------------
// Fused kernel, round-6 structure:
//  - Pass 1: coalesced fp32 A-band -> bf16 -> LDS. Pass 2: in-place row norm.
//  - Main loop, zero barriers, zero reg-copies, stage s = mt*13+kt:
//      B: 4-deep rotating register prefetch, slot = s&3  (proved in r5)
//      A: 2-deep rotating register prefetch FROM LDS, slot = s&1
//         (r5 proved all-of-A-in-regs spills: 208 arch VGPRs + bf > 256 cap)
//    mtu x4 unroll makes both slot indices compile-time.
//  - Epilogue per mt: vacc[row] += wm[col]*C^2; final shfl reduce + atomics.
// ---------------------------------------------------------------------------
__global__ __launch_bounds__(256, 1) void gemm_fused_kernel(
    const float* __restrict__ A,        // raw power_spectrum fp32 [N_ENV][DIM]
    const short8* __restrict__ Bsw,     // swizzled B fragments (+4 pad stages)
    const float* __restrict__ wm,       // [MPAD]
    const int* __restrict__ row_seg,    // [N_ENV]
    float* __restrict__ out) {          // [NSTR]
  extern __shared__ unsigned short As[];   // [128][LDST] = 108544 B

  const int tid  = threadIdx.x;
  const int lane = tid & 63;
  const int wid  = tid >> 6;
  const int wrow = wid >> 1;            // 0..1
  const int wcol = wid & 1;             // 0..1
  const long row_base = (long)blockIdx.x * BM;

  // ---- Pass 1: coalesced fp32 -> bf16 -> LDS (unnormalized) --------------
  {
    const float4* Ag = (const float4*)(A + row_base * DIM);
    int rows_valid = (int)(N_ENV - row_base);
    if (rows_valid > BM) rows_valid = BM;
#pragma unroll 5
    for (int c = tid; c < BM * (DIM / 4); c += 256) {  // 12800 float4 chunks
      int row = c / 100;                               // 100 float4 per row
      int kc  = c - row * 100;
      uint2 packed = (uint2){0u, 0u};
      if (row < rows_valid) {
        float4 v = Ag[c];
        packed.x = (unsigned int)f2bf(v.x) | ((unsigned int)f2bf(v.y) << 16);
        packed.y = (unsigned int)f2bf(v.z) | ((unsigned int)f2bf(v.w) << 16);
      }
      *(uint2*)&As[row * LDST + kc * 4] = packed;
    }
    // Zero K-pad tail [400,424): frags at kt=12, koff 16/24 read up to 416.
    if (tid < BM) {
      uint4 z = (uint4){0u, 0u, 0u, 0u};
      uint4* zp = (uint4*)&As[tid * LDST + 400];
      zp[0] = z; zp[1] = z; zp[2] = z;
    }
  }
  __syncthreads();

  // ---- Pass 2: per-row norm from LDS, scale in place ---------------------
  {
    int row = tid >> 1, half = tid & 1;
    unsigned short* rp = &As[row * LDST + half * 200];
    short8 vals[25];
    float ss = 0.f;
#pragma unroll
    for (int i = 0; i < 25; ++i) {
      vals[i] = *(const short8*)(rp + i * 8);
#pragma unroll
      for (int e = 0; e < 8; ++e) {
        float f = bf2f((unsigned short)vals[i][e]);
        ss += f * f;
      }
    }
    ss += __shfl_xor(ss, 1);
    float rn = (ss > 0.f) ? rsqrtf(ss) : 0.f;
#pragma unroll
    for (int i = 0; i < 25; ++i) {
      short8 o;
#pragma unroll
      for (int e = 0; e < 8; ++e)
        o[e] = (short)f2bf(bf2f((unsigned short)vals[i][e]) * rn);
      *(short8*)(rp + i * 8) = o;
    }
  }
  __syncthreads();
  // LDS is read-only from here; no more barriers.

  const int frow = lane & 15;
  const int koff = (lane >> 4) * 8;
  // Per-i LDS fragment base (row part); kt picks an immediate offset.
  const unsigned short* arp[4];
#pragma unroll
  for (int i = 0; i < 4; ++i)
    arp[i] = &As[(wrow * 64 + i * 16 + frow) * LDST + koff];

  float vacc[4][4];
#pragma unroll
  for (int i = 0; i < 4; ++i)
#pragma unroll
    for (int r = 0; r < 4; ++r) vacc[i][r] = 0.f;

  // ---- pipelines: af 2-deep (slot=s&1), bf 4-deep (slot=s&3) -------------
  const short8* Bb = Bsw + (size_t)(wcol * 4) * 64 + lane;  // + j*64 + s*512
  short8 af[2][4], bf[4][4];
#pragma unroll
  for (int p = 0; p < 2; ++p)                 // A frags for stages 0,1
#pragma unroll
    for (int i = 0; i < 4; ++i)
      af[p][i] = *(const short8*)(arp[i] + p * 32);
#pragma unroll
  for (int p = 0; p < 4; ++p)                 // B frags for stages 0..3
#pragma unroll
    for (int j = 0; j < 4; ++j)
      bf[p][j] = Bb[(size_t)p * 512 + j * 64];

#pragma unroll 1
  for (int mt4 = 0; mt4 < 4; ++mt4) {
    const short8* Bblk = Bb + (size_t)mt4 * (4 * KTILES * 512);
#pragma unroll
    for (int mtu = 0; mtu < 4; ++mtu) {
      float4v acc[4][4];
#pragma unroll
      for (int i = 0; i < 4; ++i)
#pragma unroll
        for (int j = 0; j < 4; ++j) acc[i][j] = (float4v){0.f, 0.f, 0.f, 0.f};

#pragma unroll
      for (int kt = 0; kt < KTILES; ++kt) {
        const int slotB = (mtu + kt) & 3;     // == (global stage) & 3
        const int slotA = (mtu + kt) & 1;     // == (global stage) & 1
        // consume stage (mt4*4+mtu, kt)
#pragma unroll
        for (int i = 0; i < 4; ++i)
#pragma unroll
          for (int j = 0; j < 4; ++j)
            acc[i][j] = __builtin_amdgcn_mfma_f32_16x16x32_bf16(
                af[slotA][i], bf[slotB][j], acc[i][j], 0, 0, 0);
        // prefetch B for stage s+4 into the slot just consumed
#pragma unroll
        for (int j = 0; j < 4; ++j)
          bf[slotB][j] = Bblk[(size_t)(mtu * KTILES + kt + 4) * 512 + j * 64];
        // prefetch A for stage s+2 (A frags are mt-invariant)
        const int kt2 = (kt + 2 < KTILES) ? kt + 2 : kt - 11;
#pragma unroll
        for (int i = 0; i < 4; ++i)
          af[slotA][i] = *(const short8*)(arp[i] + kt2 * 32);
      }

      // epilogue: vacc[row] += wm[col] * C^2 over this wave's 4 col-frags
      const int mtb = (mt4 * 4 + mtu) * BN;
      float wmv[4];
#pragma unroll
      for (int j = 0; j < 4; ++j)
        wmv[j] = wm[mtb + wcol * 64 + j * 16 + frow];
#pragma unroll
      for (int i = 0; i < 4; ++i)
#pragma unroll
        for (int r = 0; r < 4; ++r) {
          float s = 0.f;
#pragma unroll
          for (int j = 0; j < 4; ++j) {
            float c = acc[i][j][r];
            s += wmv[j] * c * c;
          }
          vacc[i][r] += s;
        }
    }
  }

  // cross-lane reduce over 16-lane groups (same C/D rows), then atomics
#pragma unroll
  for (int i = 0; i < 4; ++i)
#pragma unroll
    for (int r = 0; r < 4; ++r) {
      float s = vacc[i][r];
      s += __shfl_xor(s, 1);
      s += __shfl_xor(s, 2);
      s += __shfl_xor(s, 4);
      s += __shfl_xor(s, 8);
      if ((lane & 15) == 0) {
        long n = row_base + wrow * 64 + i * 16 + (lane >> 4) * 4 + r;
        if (n < N_ENV) atomicAdd(&out[row_seg[n]], s);
      }
    }
}

// ---------------------------------------------------------------------------
extern "C" void kernel_launch(void* const* d_in, const int* in_sizes, int n_in,
                              void* d_out, int out_size, void* d_ws, size_t ws_size,
                              hipStream_t stream) {
  const float* ps      = (const float*)d_in[0];  // [N_ENV, DIM]
  const float* sp      = (const float*)d_in[1];  // [MPTS, DIM]
  const float* w       = (const float*)d_in[2];  // [1, NTRN]
  // d_in[3] = all_species: unused by the reference
  const int*   row_seg = (const int*)d_in[4];    // [N_ENV]
  const int*   col_seg = (const int*)d_in[5];    // [MPTS]
  float* out = (float*)d_out;                    // [NSTR]

  char* ws = (char*)d_ws;
  // 208 real stages + 4 pad stages (tail prefetch reads them, never consumed)
  const size_t B_BYTES = (size_t)(NSTAGE + 4) * 512 * 16;  // 1,736,704
  short8* Bsw = (short8*)ws;
  float*  wm  = (float*)(ws + B_BYTES);

  const int LDS_BYTES = BM * LDST * 2;   // 108544
  (void)hipFuncSetAttribute((const void*)gemm_fused_kernel,
                            hipFuncAttributeMaxDynamicSharedMemorySize,
                            LDS_BYTES);

  prep_kernel<<<MPAD / 256, 256, 0, stream>>>(w, col_seg, wm, out);
  bswz_kernel<<<(NSTAGE * 8 * 64) / 256, 256, 0, stream>>>(sp, Bsw);
  gemm_fused_kernel<<<NPAD / BM, 256, LDS_BYTES, stream>>>(ps, Bsw, wm, row_seg, out);
}